// Round 14
// baseline (131.387 us; speedup 1.0000x reference)
//
#include <hip/hip_runtime.h>
#include <math.h>

#define NQ 12
#define NS 4096
#define TT 32
#define BB 256
#define HH 128
#define NT 1024

typedef float v2f __attribute__((ext_vector_type(2)));
typedef float v4f __attribute__((ext_vector_type(4)));

// ---------- compile-time CNOT-layer permutations (exactly per reference _cnot) ----------
constexpr unsigned cnot_g(unsigned x, int w, int r){
    int pc = 11 - w;                    // control wire w -> bit 11-w
    int pt = 11 - ((w + r) % 12);       // target wire (w+r)%12
    return x ^ (((x >> pc) & 1u) << pt);
}
constexpr unsigned Fperm(unsigned i, int r){      // new[i] = old[Fperm(i,r)]
    unsigned x = i;
    for (int w = 11; w >= 0; --w) x = cnot_g(x, w, r);
    return x;
}
constexpr unsigned Finv(unsigned i, int r){
    unsigned x = i;
    for (int w = 0; w < 12; ++w) x = cnot_g(x, w, r);
    return x;
}
constexpr unsigned F0closed(unsigned i){          // Fperm(.,1) closed form
    return i ^ ((i >> 1) & 0x7FFu) ^ ((i & 1u) << 10) ^ ((i & 1u) << 11);
}
constexpr bool check_all(){
    for (int b = 0; b < NQ; ++b){
        const unsigned e = 1u << b;
        if (F0closed(e) != Fperm(e,1)) return false;
        if (Fperm(Finv(e,1),1) != e) return false;
        if (Fperm(Finv(e,2),2) != e) return false;
    }
    if (F0closed(0u) != 0u || Fperm(0u,1) != 0u || Finv(0u,2) != 0u) return false;
    if (F0closed(0x5A3u) != Fperm(0x5A3u,1)) return false;
    if (Fperm(Finv(0xABCu,2),2) != 0xABCu) return false;
    return true;
}
static_assert(check_all(), "CNOT permutation closed forms wrong");
constexpr unsigned maskM(int k){
    unsigned m = 0;
    for (int b = 0; b < NQ; ++b) m |= ((Finv(1u<<b, 2) >> (11 - k)) & 1u) << b;
    return m;
}
constexpr unsigned gM0 = maskM(0), gM1 = maskM(1), gM2 = maskM(2), gM3 = maskM(3);
constexpr int sgn2(unsigned M, int K){ return __builtin_popcount((unsigned)K & (M >> 10)) & 1; }

// ---------- rank-5 swizzle for SIX layouts (1024-thread / 4-amp design) ----------
// sigma: s0=j0^j5, s1=j1^j6, s2=j2^j7, s3=j3^j4, s4=j4^j1, bits 5..11 identity.
constexpr int swz12(int j){
    int s = j;
    s ^= (j >> 5) & 7;          // s0..2 ^= j5..7
    s ^= ((j >> 4) & 1) << 3;   // s3 ^= j4
    s ^= ((j >> 1) & 1) << 4;   // s4 ^= j1
    return s;
}
constexpr unsigned jcfg(int c, unsigned tid, unsigned k){
    switch(c){
        case 0: return (tid << 2) | k;                            // A: local j0,1 (w11,10)
        case 1: return ((tid>>2)<<4) | (k<<2) | (tid&3);          // B: local j2,3 (w9,8)
        case 2: return ((tid>>4)<<6) | (k<<4) | (tid&15);         // C: local j4,5 (w7,6)
        case 3: return ((tid>>6)<<8) | (k<<6) | (tid&63);         // D: local j6,7 (w5,4)
        case 4: return ((tid>>8)<<10) | (k<<8) | (tid&255);       // E: local j8,9 (w3,2)
        default:return (k<<10) | tid;                             // F: local j10,11 (w1,0)
    }
}
// every config: exactly 2 lanes per bank-pair (b64 minimum = conflict-free)
constexpr bool banks_ok(){
    for (int c = 0; c < 6; ++c){
        int cnt[32] = {};
        for (unsigned l = 0; l < 64; ++l) cnt[swz12((int)jcfg(c, l, 0)) & 31]++;
        for (int b = 0; b < 32; ++b) if (cnt[b] != 2) return false;
    }
    return true;
}
static_assert(banks_ok(), "swizzle not conflict-free for some config");
constexpr bool bij_ok(){
    for (int hi = 0; hi < 128; ++hi){
        unsigned seen = 0;
        for (int lo = 0; lo < 32; ++lo){
            const int s = swz12((hi << 5) | lo);
            if ((s >> 5) != hi) return false;    // upper bits preserved
            seen |= 1u << (s & 31);
        }
        if (seen != 0xFFFFFFFFu) return false;
    }
    return true;
}
static_assert(bij_ok(), "swizzle not bijective");

// ---------- packed-fp32 complex helpers (VOP3P) ----------
__device__ __forceinline__ v2f pk_cmul(v2f m, v2f a){
    v2f t;
    asm("v_pk_mul_f32 %0, %1, %2 op_sel:[0,0] op_sel_hi:[0,1]"
        : "=v"(t) : "v"(m), "v"(a));
    asm("v_pk_fma_f32 %0, %1, %2, %0 op_sel:[1,1,0] op_sel_hi:[1,0,1] neg_lo:[1,0,0]"
        : "+v"(t) : "v"(m), "v"(a));
    return t;
}
template<int NL, int NH>
__device__ __forceinline__ void pk_accsgn(v2f &acc, v2f ppb){
    if constexpr (NL==0 && NH==0)
        asm("v_pk_add_f32 %0, %1, %0" : "+v"(acc) : "v"(ppb));
    else if constexpr (NL==1 && NH==0)
        asm("v_pk_add_f32 %0, %1, %0 neg_lo:[1,0]" : "+v"(acc) : "v"(ppb));
    else if constexpr (NL==0 && NH==1)
        asm("v_pk_add_f32 %0, %1, %0 neg_hi:[1,0]" : "+v"(acc) : "v"(ppb));
    else
        asm("v_pk_add_f32 %0, %1, %0 neg_lo:[1,0] neg_hi:[1,0]" : "+v"(acc) : "v"(ppb));
}
template<int K>
__device__ __forceinline__ void expk4(const v2f* amp, v2f &a01, v2f &a23){
    const float pp = fmaf(amp[K].x, amp[K].x, amp[K].y * amp[K].y);
    v2f ppb; ppb.x = pp; ppb.y = pp;
    pk_accsgn<sgn2(gM0,K), sgn2(gM1,K)>(a01, ppb);
    pk_accsgn<sgn2(gM2,K), sgn2(gM3,K)>(a23, ppb);
    if constexpr (K < 3) expk4<K+1>(amp, a01, a23);
}

// ---------- DPP helpers ----------
template<int C>
__device__ __forceinline__ float dppadd(float v){
    return v + __int_as_float(
        __builtin_amdgcn_update_dpp(0, __float_as_int(v), C, 0xF, 0xF, true));
}
__device__ __forceinline__ float wsum(float v){        // total in lane 63
    v = dppadd<0x111>(v);   // row_shr:1
    v = dppadd<0x112>(v);   // row_shr:2
    v = dppadd<0x114>(v);   // row_shr:4
    v = dppadd<0x118>(v);   // row_shr:8
    v = dppadd<0x142>(v);   // row_bcast:15
    v = dppadd<0x143>(v);   // row_bcast:31
    return v;
}
__device__ __forceinline__ float bfsum16(float v){     // 16-lane butterfly, all lanes
    v = dppadd<0xB1>(v);    // quad_perm xor1
    v = dppadd<0x4E>(v);    // quad_perm xor2
    v = dppadd<0x141>(v);   // row_half_mirror (xor7)
    v = dppadd<0x140>(v);   // row_mirror (xor15)
    return v;
}
template<int CTRL>
__device__ __forceinline__ float qpermf(float v){
    return __int_as_float(
        __builtin_amdgcn_update_dpp(0, __float_as_int(v), CTRL, 0xF, 0xF, true));
}
template<int CTRL>
__device__ __forceinline__ v4f qperm4(v4f v){
    v4f r;
    r.x = qpermf<CTRL>(v.x); r.y = qpermf<CTRL>(v.y);
    r.z = qpermf<CTRL>(v.z); r.w = qpermf<CTRL>(v.w);
    return r;
}

__device__ __forceinline__ float fsig(float xv){ return __fdividef(1.f, 1.f + __expf(-xv)); }
__device__ __forceinline__ float ftanh(float xv){
    const float e = __expf(-2.f * xv);
    return __fdividef(1.f - e, 1.f + e);
}

// 2 RY gates on the 2 thread-local bits: lb0 -> wire WTOP, lb1 -> wire WTOP-1
template<int WTOP>
__device__ __forceinline__ void rot2ry(v2f* s, const v2f* G){
    {
        const float cw = G[WTOP].x, sw = G[WTOP].y;
        #pragma unroll
        for (int m = 0; m < 4; m += 2){
            const v2f a = s[m], b = s[m+1];
            s[m]   = a*cw - b*sw;
            s[m+1] = a*sw + b*cw;
        }
    }
    {
        const float cw = G[WTOP-1].x, sw = G[WTOP-1].y;
        #pragma unroll
        for (int m = 0; m < 2; ++m){
            const v2f a = s[m], b = s[m+2];
            s[m]   = a*cw - b*sw;
            s[m+2] = a*sw + b*cw;
        }
    }
}

// amdgpu_waves_per_eu(4,4): pins occupancy CEILING to 4 waves/EU -> register
// budget 512/4 = 128 VGPR (launch_bounds' 2nd arg only sets the MIN, which
// left the allocator targeting 8 waves/EU = 64 VGPR -> 17 MB of spills in R12/13)
extern "C" __global__ void __launch_bounds__(NT)
__attribute__((amdgpu_waves_per_eu(4, 4)))
qlstm_kernel(const float* __restrict__ x,  const float* __restrict__ h0,
             const float* __restrict__ c0, const float* __restrict__ qw,
             const float* __restrict__ Wf, const float* __restrict__ bfp,
             const float* __restrict__ Wi, const float* __restrict__ bip,
             const float* __restrict__ Wc, const float* __restrict__ bcp,
             const float* __restrict__ Wo, const float* __restrict__ bop,
             float* __restrict__ out)
{
    __shared__ v2f S[NS];                  // state buffer (swz12), 32 KB
    __shared__ v2f matp[NQ][4];            // layer-0 Rot matrices
    __shared__ v2f vvx[8][2];              // x-wire product vectors (this step)
    __shared__ float xs[TT*8];
    __shared__ float4 red4[16];            // per-wave partials
    __shared__ float4 qh[TT];              // q history for epilogue

    const int b    = blockIdx.x;
    const int tid  = threadIdx.x;
    const int wave = tid >> 6;
    const int lane = tid & 63;

    // ---- one-time init: layer-0 matrices ----
    if (tid < NQ){
        const int w = tid;
        const float phi = qw[w*3 + 0];
        const float th  = qw[w*3 + 1];
        const float om  = qw[w*3 + 2];
        float cth, sth, cap, sap, cam, sam;
        sincosf(0.5f*th, &sth, &cth);
        sincosf(0.5f*(phi+om), &sap, &cap);
        sincosf(0.5f*(phi-om), &sam, &cam);
        v2f m00; m00.x =  cap*cth; m00.y = -sap*cth;
        v2f m01; m01.x = -cam*sth; m01.y = -sam*sth;
        v2f m10; m10.x =  cam*sth; m10.y = -sam*sth;
        v2f m11; m11.x =  cap*cth; m11.y =  sap*cth;
        matp[w][0] = m00; matp[w][1] = m01;
        matp[w][2] = m10; matp[w][3] = m11;
    }
    if (tid >= 256 && tid < 512) xs[tid - 256] = x[b*(TT*8) + (tid - 256)];

    // ---- layer-1 constants: RY (c,s); Dphi folds on RAW j bits ----
    // j = tid<<2 | k: wire w phase bit = j bit (11-w): w=0..9 -> tid bit (9-w); w=10 -> k1; w=11 -> k0
    v2f G[NQ];
    #pragma unroll
    for (int w = 0; w < NQ; ++w){
        float cg, sg; sincosf(0.5f*qw[(NQ + w)*3 + 1], &sg, &cg);
        G[w].x = cg; G[w].y = sg;
    }
    v2f Zphi;
    {
        float A = 0.f;
        #pragma unroll
        for (int w = 0; w <= 9; ++w){
            const float ph = 0.5f*qw[(NQ + w)*3 + 0];
            A += ((tid >> (9 - w)) & 1) ? ph : -ph;
        }
        float sa, ca; sincosf(A, &sa, &ca);
        Zphi.x = ca; Zphi.y = sa;
    }
    v2f dd[4];
    {
        const float f10 = 0.5f*qw[(NQ + 10)*3 + 0];
        const float f11 = 0.5f*qw[(NQ + 11)*3 + 0];
        #pragma unroll
        for (int k = 0; k < 4; ++k){
            const float P = (((k>>1)&1) ? f10 : -f10) + ((k&1) ? f11 : -f11);
            float sp, cp; sincosf(P, &sp, &cp);
            dd[k].x = cp; dd[k].y = sp;
        }
    }

    // chain constants for wire cw = tid&3 (h-wires 8+cw), every lane
    const int cw = tid & 3;
    const float WfC=Wf[cw], bfC=bfp[cw], WiC=Wi[cw], biC=bip[cw];
    const float WcC=Wc[cw], bcC=bcp[cw], WoC=Wo[cw], boC=bop[cw];
    float c4 = c0[b*HH + cw];
    const float h_init = h0[b*HH + cw];
    __syncthreads();

    const v2f M8w0 = matp[8+cw][0], M8w1 = matp[8+cw][1];
    const v2f M8w2 = matp[8+cw][2], M8w3 = matp[8+cw][3];

    // t=0 x-wire vvx by threads 128..135
    if (tid >= 128 && tid < 136){
        const int w = tid - 128;
        float sa, ca; sincosf(0.5f*xs[w], &sa, &ca);
        const v2f M00=matp[w][0], M01=matp[w][1], M10=matp[w][2], M11=matp[w][3];
        v2f t0v; t0v.x = M00.x*ca + M01.y*sa; t0v.y = M00.y*ca - M01.x*sa;
        v2f t1v; t1v.x = M10.x*ca + M11.y*sa; t1v.y = M10.y*ca - M11.x*sa;
        vvx[w][0] = t0v; vvx[w][1] = t1v;
    }
    // t=0 h-wire vectors via qperm broadcast (quad lane j <-> cw==j)
    v4f hv0, hv1, hv2, hv3;
    {
        float sa, ca; sincosf(0.5f*h_init, &sa, &ca);
        v4f hw;
        hw.x = M8w0.x*ca + M8w1.y*sa;  hw.y = M8w0.y*ca - M8w1.x*sa;
        hw.z = M8w2.x*ca + M8w3.y*sa;  hw.w = M8w2.y*ca - M8w3.x*sa;
        hv0 = qperm4<0x00>(hw); hv1 = qperm4<0x55>(hw);
        hv2 = qperm4<0xAA>(hw); hv3 = qperm4<0xFF>(hw);
    }
    __syncthreads();

    // ---- per-thread constants ----
    const float sg0 = (__builtin_parity(tid & (gM0 & 0x3FFu)) ? -1.f : 1.f);
    const float sg1 = (__builtin_parity(tid & (gM1 & 0x3FFu)) ? -1.f : 1.f);
    const float sg2 = (__builtin_parity(tid & (gM2 & 0x3FFu)) ? -1.f : 1.f);
    const float sg3 = (__builtin_parity(tid & (gM3 & 0x3FFu)) ? -1.f : 1.f);
    // swizzled bases + compile-time per-k masks for the 6 configs
    const int bA = swz12((int)jcfg(0, (unsigned)tid, 0));
    const int bB = swz12((int)jcfg(1, (unsigned)tid, 0));
    const int bC = swz12((int)jcfg(2, (unsigned)tid, 0));
    const int bD = swz12((int)jcfg(3, (unsigned)tid, 0));
    const int bE = swz12((int)jcfg(4, (unsigned)tid, 0));
    const int bF = swz12((int)jcfg(5, (unsigned)tid, 0));
    // F0 product selectors (j = tid<<2|k): F0_b = j_b ^ j_{b+1} (b<=9), F0_10 = j10^j11^j0, F0_11 = j11^j0
    const int s2 = ((tid>>7) ^ (tid>>8)) & 1;   // wire 2
    const int s3 = ((tid>>6) ^ (tid>>7)) & 1;
    const int s4 = ((tid>>5) ^ (tid>>6)) & 1;
    const int s5 = ((tid>>4) ^ (tid>>5)) & 1;
    const int s6 = ((tid>>3) ^ (tid>>4)) & 1;
    const int s7 = ((tid>>2) ^ (tid>>3)) & 1;   // wire 7
    const int s8 = ((tid>>1) ^ (tid>>2)) & 1;   // wire 8 (h)
    const int s9 = ( tid     ^ (tid>>1)) & 1;   // wire 9 (h)
    const int t9s  = (tid >> 9) & 1;            // wire 0 base sel (x)
    const int t89s = ((tid>>8) ^ (tid>>9)) & 1; // wire 1 base sel (x)
    const int t0   = tid & 1;                   // wire 10 base sel (h)
    const v2f* vf = &vvx[0][0];

    // ---- carried x-only product parts ----
    v2f QxZ, Ux0, Ux1;
    {
        const v2f e2 = vf[ 4+s2], e3 = vf[ 6+s3], e4 = vf[ 8+s4];
        const v2f e5 = vf[10+s5], e6 = vf[12+s6], e7 = vf[14+s7];
        QxZ = pk_cmul(pk_cmul(pk_cmul(e2,e3), pk_cmul(e4,e5)),
                      pk_cmul(pk_cmul(e6,e7), Zphi));
        Ux0 = pk_cmul(vf[0+t9s],     vf[2+t89s]);       // wire0 sel t9^k0, wire1 sel t8^t9^k0
        Ux1 = pk_cmul(vf[0+(t9s^1)], vf[2+(t89s^1)]);
    }

    v2f amp[4];

    #pragma unroll 1
    for (int t = 0; t < TT; ++t){
        // ---- finish product with h parts; amp[k] = prod[F0(j)] * Zphi * dd[k] ----
        v2f e8v;  e8v.x = s8 ? hv0.z : hv0.x;  e8v.y = s8 ? hv0.w : hv0.y;
        v2f e9v;  e9v.x = s9 ? hv1.z : hv1.x;  e9v.y = s9 ? hv1.w : hv1.y;
        const v2f QH  = pk_cmul(QxZ, pk_cmul(e8v, e9v));
        const v2f QU0 = pk_cmul(QH, Ux0);
        const v2f QU1 = pk_cmul(QH, Ux1);
        v2f v10a; v10a.x = t0 ? hv2.z : hv2.x;  v10a.y = t0 ? hv2.w : hv2.y;   // k1=0
        v2f v10b; v10b.x = t0 ? hv2.x : hv2.z;  v10b.y = t0 ? hv2.y : hv2.w;   // k1=1
        v2f v11a; v11a.x = hv3.x; v11a.y = hv3.y;   // k0^k1 = 0
        v2f v11b; v11b.x = hv3.z; v11b.y = hv3.w;   // k0^k1 = 1
        amp[0] = pk_cmul(pk_cmul(QU0, v10a), pk_cmul(v11a, dd[0]));
        amp[1] = pk_cmul(pk_cmul(QU1, v10a), pk_cmul(v11b, dd[1]));
        amp[2] = pk_cmul(pk_cmul(QU0, v10b), pk_cmul(v11b, dd[2]));
        amp[3] = pk_cmul(pk_cmul(QU1, v10b), pk_cmul(v11a, dd[3]));

        // ---- 12 RY gates, 6 rounds; T1-T3 wave-local (fence), T4/T5 barriers ----
        rot2ry<11>(amp, G);                                     // wires 11,10
        #pragma unroll
        for (int k = 0; k < 4; ++k) S[bA ^ swz12((int)jcfg(0,0,k))] = amp[k];
        asm volatile("" ::: "memory");
        #pragma unroll
        for (int k = 0; k < 4; ++k) amp[k] = S[bB ^ swz12((int)jcfg(1,0,k))];
        rot2ry<9>(amp, G);                                      // wires 9,8
        #pragma unroll
        for (int k = 0; k < 4; ++k) S[bB ^ swz12((int)jcfg(1,0,k))] = amp[k];
        asm volatile("" ::: "memory");
        #pragma unroll
        for (int k = 0; k < 4; ++k) amp[k] = S[bC ^ swz12((int)jcfg(2,0,k))];
        rot2ry<7>(amp, G);                                      // wires 7,6
        #pragma unroll
        for (int k = 0; k < 4; ++k) S[bC ^ swz12((int)jcfg(2,0,k))] = amp[k];
        asm volatile("" ::: "memory");
        #pragma unroll
        for (int k = 0; k < 4; ++k) amp[k] = S[bD ^ swz12((int)jcfg(3,0,k))];
        rot2ry<5>(amp, G);                                      // wires 5,4
        #pragma unroll
        for (int k = 0; k < 4; ++k) S[bD ^ swz12((int)jcfg(3,0,k))] = amp[k];
        __syncthreads();                                        // bar_a (cross-wave)
        #pragma unroll
        for (int k = 0; k < 4; ++k) amp[k] = S[bE ^ swz12((int)jcfg(4,0,k))];
        rot2ry<3>(amp, G);                                      // wires 3,2
        #pragma unroll
        for (int k = 0; k < 4; ++k) S[bE ^ swz12((int)jcfg(4,0,k))] = amp[k];
        __syncthreads();                                        // bar_b (cross-wave)
        #pragma unroll
        for (int k = 0; k < 4; ++k) amp[k] = S[bF ^ swz12((int)jcfg(5,0,k))];
        rot2ry<1>(amp, G);                                      // wires 1,0

        // ---- CNOT layer 1 folded into <Z_g>; j = (k<<10)|tid ----
        v2f a01; a01.x = 0.f; a01.y = 0.f;
        v2f a23; a23.x = 0.f; a23.y = 0.f;
        expk4<0>(amp, a01, a23);
        float p0 = a01.x * sg0, p1 = a01.y * sg1;
        float p2s = a23.x * sg2, p3 = a23.y * sg3;
        p0 = wsum(p0); p1 = wsum(p1); p2s = wsum(p2s); p3 = wsum(p3);
        if (lane == 63) red4[wave] = make_float4(p0, p1, p2s, p3);
        // next step's x-wire vvx
        if (tid >= 128 && tid < 136){
            const int w  = tid - 128;
            const int tn = (t + 1 < TT) ? t + 1 : t;
            float sa, ca; __sincosf(0.5f*xs[tn*8 + w], &sa, &ca);
            const v2f M00=matp[w][0], M01=matp[w][1], M10=matp[w][2], M11=matp[w][3];
            v2f t0v; t0v.x = M00.x*ca + M01.y*sa; t0v.y = M00.y*ca - M01.x*sa;
            v2f t1v; t1v.x = M10.x*ca + M11.y*sa; t1v.y = M10.y*ca - M11.x*sa;
            vvx[w][0] = t0v; vvx[w][1] = t1v;
        }
        __syncthreads();                                        // bar_c (red4 + vvx)

        // ---- cross-wave q via single b128 read + 16-lane DPP butterfly ----
        const float4 r = red4[lane & 15];
        float q0 = bfsum16(r.x), q1 = bfsum16(r.y);
        float q2 = bfsum16(r.z), q3 = bfsum16(r.w);

        // ---- x-only parts for t+1 (fills transcendental bubbles below) ----
        {
            const v2f e2 = vf[ 4+s2], e3 = vf[ 6+s3], e4 = vf[ 8+s4];
            const v2f e5 = vf[10+s5], e6 = vf[12+s6], e7 = vf[14+s7];
            QxZ = pk_cmul(pk_cmul(pk_cmul(e2,e3), pk_cmul(e4,e5)),
                          pk_cmul(pk_cmul(e6,e7), Zphi));
            Ux0 = pk_cmul(vf[0+t9s],     vf[2+t89s]);
            Ux1 = pk_cmul(vf[0+(t9s^1)], vf[2+(t89s^1)]);
        }

        if (tid == 0) qh[t] = make_float4(q0, q1, q2, q3);

        // ---- tail: each lane computes wire (8+cw)'s chain; qperm broadcast ----
        {
            const float fg = fsig (q0*WfC + bfC);
            const float ig = fsig (q1*WiC + biC);
            const float cg = ftanh(q2*WcC + bcC);
            const float og = fsig (q3*WoC + boC);
            c4 = fg*c4 + ig*cg;
            const float hj = og * ftanh(c4);
            float sa, ca; __sincosf(0.5f*hj, &sa, &ca);
            v4f hw;
            hw.x = M8w0.x*ca + M8w1.y*sa;  hw.y = M8w0.y*ca - M8w1.x*sa;
            hw.z = M8w2.x*ca + M8w3.y*sa;  hw.w = M8w2.y*ca - M8w3.x*sa;
            hv0 = qperm4<0x00>(hw); hv1 = qperm4<0x55>(hw);
            hv2 = qperm4<0xAA>(hw); hv3 = qperm4<0xFF>(hw);
        }
    }

    // ---- epilogue: per-channel LSTM scan over q history ----
    __syncthreads();
    if (tid < HH){
        const float wfE=Wf[tid], bfE=bfp[tid], wiE=Wi[tid], biE=bip[tid];
        const float wcE=Wc[tid], bcE=bcp[tid], woE=Wo[tid], boE=bop[tid];
        float cc = c0[b*HH + tid];
        float hh = 0.f;
        #pragma unroll 1
        for (int t = 0; t < TT; ++t){
            const float4 q = qh[t];
            const float fg = fsig (q.x*wfE + bfE);
            const float ig = fsig (q.y*wiE + biE);
            const float cg = ftanh(q.z*wcE + bcE);
            const float og = fsig (q.w*woE + boE);
            cc = fg*cc + ig*cg;
            hh = og * ftanh(cc);
        }
        out[b*HH + tid]         = hh;
        out[BB*HH + b*HH + tid] = cc;
    }
}

extern "C" void kernel_launch(void* const* d_in, const int* in_sizes, int n_in,
                              void* d_out, int out_size, void* d_ws, size_t ws_size,
                              hipStream_t stream)
{
    (void)in_sizes; (void)n_in; (void)d_ws; (void)ws_size; (void)out_size;
    const float* x  = (const float*)d_in[0];
    const float* h0 = (const float*)d_in[1];
    const float* c0 = (const float*)d_in[2];
    const float* qw = (const float*)d_in[3];
    const float* Wf = (const float*)d_in[4];
    const float* bf = (const float*)d_in[5];
    const float* Wi = (const float*)d_in[6];
    const float* bi = (const float*)d_in[7];
    const float* Wc = (const float*)d_in[8];
    const float* bc = (const float*)d_in[9];
    const float* Wo = (const float*)d_in[10];
    const float* bo = (const float*)d_in[11];
    qlstm_kernel<<<BB, NT, 0, stream>>>(x, h0, c0, qw, Wf, bf, Wi, bi,
                                        Wc, bc, Wo, bo, (float*)d_out);
}

// Round 15
// 93.159 us; speedup vs baseline: 1.4104x; 1.4104x over previous
//
#include <hip/hip_runtime.h>
#include <math.h>

#define NQ 12
#define NS 4096
#define TT 32
#define BB 256
#define HH 128
#define NT 512

typedef float v2f __attribute__((ext_vector_type(2)));
typedef float v4f __attribute__((ext_vector_type(4)));

// ---------- compile-time CNOT-layer permutations (exactly per reference _cnot) ----------
constexpr unsigned cnot_g(unsigned x, int w, int r){
    int pc = 11 - w;                    // control wire w -> bit 11-w
    int pt = 11 - ((w + r) % 12);       // target wire (w+r)%12
    return x ^ (((x >> pc) & 1u) << pt);
}
constexpr unsigned Fperm(unsigned i, int r){      // new[i] = old[Fperm(i,r)]
    unsigned x = i;
    for (int w = 11; w >= 0; --w) x = cnot_g(x, w, r);
    return x;
}
constexpr unsigned Finv(unsigned i, int r){
    unsigned x = i;
    for (int w = 0; w < 12; ++w) x = cnot_g(x, w, r);
    return x;
}
constexpr unsigned F0closed(unsigned i){          // Fperm(.,1) closed form
    return i ^ ((i >> 1) & 0x7FFu) ^ ((i & 1u) << 10) ^ ((i & 1u) << 11);
}
constexpr bool check_all(){
    for (int b = 0; b < NQ; ++b){
        const unsigned e = 1u << b;
        if (F0closed(e) != Fperm(e,1)) return false;
        if (Fperm(Finv(e,1),1) != e) return false;
        if (Fperm(Finv(e,2),2) != e) return false;
    }
    if (F0closed(0u) != 0u || Fperm(0u,1) != 0u || Finv(0u,2) != 0u) return false;
    if (F0closed(0x5A3u) != Fperm(0x5A3u,1)) return false;
    if (Fperm(Finv(0xABCu,2),2) != 0xABCu) return false;
    return true;
}
static_assert(check_all(), "CNOT permutation closed forms wrong");
constexpr unsigned maskM(int k){
    unsigned m = 0;
    for (int b = 0; b < NQ; ++b) m |= ((Finv(1u<<b, 2) >> (11 - k)) & 1u) << b;
    return m;
}
constexpr unsigned gM0 = maskM(0), gM1 = maskM(1), gM2 = maskM(2), gM3 = maskM(3);
constexpr int sgn9(unsigned M, int K){ return __builtin_popcount((unsigned)K & (M >> 9)) & 1; }

// ---------- packed-fp32 complex helpers (VOP3P) ----------
__device__ __forceinline__ v2f pk_cmul(v2f m, v2f a){
    v2f t;
    asm("v_pk_mul_f32 %0, %1, %2 op_sel:[0,0] op_sel_hi:[0,1]"
        : "=v"(t) : "v"(m), "v"(a));
    asm("v_pk_fma_f32 %0, %1, %2, %0 op_sel:[1,1,0] op_sel_hi:[1,0,1] neg_lo:[1,0,0]"
        : "+v"(t) : "v"(m), "v"(a));
    return t;
}
template<int NL, int NH>
__device__ __forceinline__ void pk_accsgn(v2f &acc, v2f ppb){
    if constexpr (NL==0 && NH==0)
        asm("v_pk_add_f32 %0, %1, %0" : "+v"(acc) : "v"(ppb));
    else if constexpr (NL==1 && NH==0)
        asm("v_pk_add_f32 %0, %1, %0 neg_lo:[1,0]" : "+v"(acc) : "v"(ppb));
    else if constexpr (NL==0 && NH==1)
        asm("v_pk_add_f32 %0, %1, %0 neg_hi:[1,0]" : "+v"(acc) : "v"(ppb));
    else
        asm("v_pk_add_f32 %0, %1, %0 neg_lo:[1,0] neg_hi:[1,0]" : "+v"(acc) : "v"(ppb));
}
template<int K>
__device__ __forceinline__ void expk(const v2f* amp, v2f &a01, v2f &a23){
    const float pp = fmaf(amp[K].x, amp[K].x, amp[K].y * amp[K].y);
    v2f ppb; ppb.x = pp; ppb.y = pp;
    pk_accsgn<sgn9(gM0,K), sgn9(gM1,K)>(a01, ppb);
    pk_accsgn<sgn9(gM2,K), sgn9(gM3,K)>(a23, ppb);
    if constexpr (K < 7) expk<K+1>(amp, a01, a23);
}

// ---------- DPP helpers (VALU-only cross-lane) ----------
template<int C>
__device__ __forceinline__ float dppadd(float v){
    return v + __int_as_float(
        __builtin_amdgcn_update_dpp(0, __float_as_int(v), C, 0xF, 0xF, true));
}
__device__ __forceinline__ float wsum(float v){
    v = dppadd<0x111>(v);   // row_shr:1
    v = dppadd<0x112>(v);   // row_shr:2
    v = dppadd<0x114>(v);   // row_shr:4
    v = dppadd<0x118>(v);   // row_shr:8  -> lane15 of each row16 = row sum
    v = dppadd<0x142>(v);   // row_bcast:15 -> lane31 = rows0+1, lane63 = rows2+3
    v = dppadd<0x143>(v);   // row_bcast:31 -> lane63 = total
    return v;
}
// quad_perm broadcast: every lane gets quad-lane J's value (ctrl = J*0x55)
template<int CTRL>
__device__ __forceinline__ float qpermf(float v){
    return __int_as_float(
        __builtin_amdgcn_update_dpp(0, __float_as_int(v), CTRL, 0xF, 0xF, true));
}
template<int CTRL>
__device__ __forceinline__ v4f qperm4(v4f v){
    v4f r;
    r.x = qpermf<CTRL>(v.x); r.y = qpermf<CTRL>(v.y);
    r.z = qpermf<CTRL>(v.z); r.w = qpermf<CTRL>(v.w);
    return r;
}

// ---------- rank-5 bank swizzle: slot(j) = j ^ ((j>>3)&0x1F) ----------
// (validated R7-R11: SQ_LDS_BANK_CONFLICT ~ 0; T1/T2 wave-local, T3 cross-wave)

__device__ __forceinline__ float fsig(float xv){ return __fdividef(1.f, 1.f + __expf(-xv)); }
__device__ __forceinline__ float ftanh(float xv){
    const float e = __expf(-2.f * xv);
    return __fdividef(1.f - e, 1.f + e);
}

// 3 layer-1 RY gates on the 3 thread-local bits (RZ phases folded out)
template<int WTOP>
__device__ __forceinline__ void rot3ry(v2f* s, const v2f* G){
    #pragma unroll
    for (int lb = 0; lb < 3; ++lb){
        const float cw = G[WTOP-lb].x, sw = G[WTOP-lb].y;
        #pragma unroll
        for (int k = 0; k < 8; ++k){
            if (k & (1 << lb)) continue;
            const int k1 = k | (1 << lb);
            const v2f a = s[k], b = s[k1];
            s[k]  = a*cw - b*sw;
            s[k1] = a*sw + b*cw;
        }
    }
}

extern "C" __global__ void __launch_bounds__(NT)
qlstm_kernel(const float* __restrict__ x,  const float* __restrict__ h0,
             const float* __restrict__ c0, const float* __restrict__ qw,
             const float* __restrict__ Wf, const float* __restrict__ bfp,
             const float* __restrict__ Wi, const float* __restrict__ bip,
             const float* __restrict__ Wc, const float* __restrict__ bcp,
             const float* __restrict__ Wo, const float* __restrict__ bop,
             float* __restrict__ out)
{
    __shared__ v2f S[NS];                  // single state buffer (rank-5 swizzled)
    __shared__ v2f matp[NQ][4];            // layer-0 Rot matrices (full, for vv build)
    __shared__ v2f vvx[8][2];              // x-wire product-state vectors (this step)
    __shared__ float xs[TT*8];             // preloaded x for this batch element
    __shared__ float4 red4[8];             // per-wave partial expectations
    __shared__ float4 qh[TT];              // q history for epilogue LSTM scan

    const int b    = blockIdx.x;
    const int tid  = threadIdx.x;
    const int wave = tid >> 6;
    const int lane = tid & 63;

    // ---- one-time init: layer-0 matrices ----
    if (tid < NQ){
        const int w = tid;
        const float phi = qw[w*3 + 0];
        const float th  = qw[w*3 + 1];
        const float om  = qw[w*3 + 2];
        float cth, sth, cap, sap, cam, sam;
        sincosf(0.5f*th, &sth, &cth);
        sincosf(0.5f*(phi+om), &sap, &cap);
        sincosf(0.5f*(phi-om), &sam, &cam);
        v2f m00; m00.x =  cap*cth; m00.y = -sap*cth;
        v2f m01; m01.x = -cam*sth; m01.y = -sam*sth;
        v2f m10; m10.x =  cam*sth; m10.y = -sam*sth;
        v2f m11; m11.x =  cap*cth; m11.y =  sap*cth;
        matp[w][0] = m00; matp[w][1] = m01;
        matp[w][2] = m10; matp[w][3] = m11;
    }
    if (tid >= 256) xs[tid - 256] = x[b*(TT*8) + (tid - 256)];

    // ---- layer-1 per-thread constants: RY (c,s), Dphi folds ----
    // wire w <-> j bit 11-w; j = (tid<<3)|k: wires 0..8 -> tid bits 8..0; wires 9,10,11 -> k bits 2,1,0
    v2f G[NQ];
    #pragma unroll
    for (int w = 0; w < NQ; ++w){
        float cg, sg; sincosf(0.5f*qw[(NQ + w)*3 + 1], &sg, &cg);
        G[w].x = cg; G[w].y = sg;
    }
    v2f Zphi;
    {
        float A = 0.f;
        #pragma unroll
        for (int w = 0; w <= 8; ++w){
            const float ph = qw[(NQ + w)*3 + 0];
            A += ((tid >> (8 - w)) & 1) ? ph : -ph;
        }
        float sa, ca; sincosf(0.5f*A, &sa, &ca);
        Zphi.x = ca; Zphi.y = sa;
    }
    v2f dd[8];
    {
        const float p9  = qw[(NQ + 9)*3 + 0];
        const float p10 = qw[(NQ +10)*3 + 0];
        const float p11 = qw[(NQ +11)*3 + 0];
        #pragma unroll
        for (int k = 0; k < 8; ++k){
            const float Bq = 0.5f*(((k&4)? p9 : -p9) + ((k&2)? p10 : -p10) + ((k&1)? p11 : -p11));
            float sb, cb; sincosf(Bq, &sb, &cb);
            dd[k].x = cb; dd[k].y = sb;
        }
    }

    // chain constants for wire cw = tid&3 (h-wires 8+cw), every lane
    const int cw = tid & 3;
    const float WfC=Wf[cw], bfC=bfp[cw], WiC=Wi[cw], biC=bip[cw];
    const float WcC=Wc[cw], bcC=bcp[cw], WoC=Wo[cw], boC=bop[cw];
    float c4 = c0[b*HH + cw];
    const float h_init = h0[b*HH + cw];
    __syncthreads();

    // hoist chain matrices (layer-0, wire 8+cw)
    const v2f M8w0 = matp[8+cw][0], M8w1 = matp[8+cw][1];
    const v2f M8w2 = matp[8+cw][2], M8w3 = matp[8+cw][3];

    // t=0 x-wire vvx by threads 128..135
    if (tid >= 128 && tid < 136){
        const int w = tid - 128;
        float sa, ca; sincosf(0.5f*xs[w], &sa, &ca);
        const v2f M00=matp[w][0], M01=matp[w][1], M10=matp[w][2], M11=matp[w][3];
        v2f t0v; t0v.x = M00.x*ca + M01.y*sa; t0v.y = M00.y*ca - M01.x*sa;
        v2f t1v; t1v.x = M10.x*ca + M11.y*sa; t1v.y = M10.y*ca - M11.x*sa;
        vvx[w][0] = t0v; vvx[w][1] = t1v;
    }
    // t=0 h-wire vectors: each lane computes its own wire's vector, DPP quad-broadcast
    // (quad lane j has cw==j, so qperm:[j,j,j,j] == per-wire broadcast)
    v4f hv0, hv1, hv2, hv3;
    {
        float sa, ca; sincosf(0.5f*h_init, &sa, &ca);
        v4f hw;
        hw.x = M8w0.x*ca + M8w1.y*sa;  hw.y = M8w0.y*ca - M8w1.x*sa;
        hw.z = M8w2.x*ca + M8w3.y*sa;  hw.w = M8w2.y*ca - M8w3.x*sa;
        hv0 = qperm4<0x00>(hw); hv1 = qperm4<0x55>(hw);
        hv2 = qperm4<0xAA>(hw); hv3 = qperm4<0xFF>(hw);
    }
    __syncthreads();

    // ---- per-thread constants ----
    const float sg0 = (__builtin_parity(tid & (gM0 & 0x1FFu)) ? -1.f : 1.f);
    const float sg1 = (__builtin_parity(tid & (gM1 & 0x1FFu)) ? -1.f : 1.f);
    const float sg2 = (__builtin_parity(tid & (gM2 & 0x1FFu)) ? -1.f : 1.f);
    const float sg3 = (__builtin_parity(tid & (gM3 & 0x1FFu)) ? -1.f : 1.f);
    const int bA = (tid << 3) ^ (tid & 31);                                  // cfg A: ^ k
    const int bB = (tid & 7) ^ (((tid >> 3) & 3) << 3) ^ ((tid >> 3) << 6);  // cfg B: ^ 9k
    const int bC = ((tid & 63) ^ ((tid >> 3) & 7)) | ((tid >> 6) << 9);      // cfg C: ^ (k<<6 | (k&3)<<3)
    const int bD = tid ^ ((tid >> 3) & 31);                                  // cfg D: + (k<<9)
    const int s2 = ((tid>>6) ^ (tid>>7)) & 1;
    const int s3 = ((tid>>5) ^ (tid>>6)) & 1;
    const int s4 = ((tid>>4) ^ (tid>>5)) & 1;
    const int s5 = ((tid>>3) ^ (tid>>4)) & 1;
    const int s6 = ((tid>>2) ^ (tid>>3)) & 1;
    const int s7 = ((tid>>1) ^ (tid>>2)) & 1;
    const int s8 = ( tid     ^ (tid>>1)) & 1;
    const int t8  = (tid >> 8) & 1;
    const int t78 = ((tid>>7) ^ (tid>>8)) & 1;
    const int t0  = tid & 1;
    const v2f* vf = &vvx[0][0];

    // ---- carried x-only product parts (software pipeline across the backedge) ----
    v2f QxZ, Ux0, Ux1;
    {
        const v2f e2 = vf[ 4+s2], e3 = vf[ 6+s3], e4 = vf[ 8+s4];
        const v2f e5 = vf[10+s5], e6 = vf[12+s6], e7 = vf[14+s7];
        QxZ = pk_cmul(pk_cmul(pk_cmul(e2,e3), pk_cmul(e4,e5)),
                      pk_cmul(pk_cmul(e6,e7), Zphi));
        const v2f v0a = vf[0], v0b = vf[1], v1a = vf[2], v1b = vf[3];
        const v2f ua0 = t8 ? v0b : v0a,  ua1 = t8 ? v0a : v0b;
        const v2f ub0 = t78 ? v1b : v1a, ub1 = t78 ? v1a : v1b;
        Ux0 = pk_cmul(ua0, ub0); Ux1 = pk_cmul(ua1, ub1);
    }

    v2f amp[8];

    #pragma unroll 1
    for (int t = 0; t < TT; ++t){
        // ---- finish product build with h-dependent parts ----
        v2f e8; e8.x = s8 ? hv0.z : hv0.x;  e8.y = s8 ? hv0.w : hv0.y;
        const v2f Q   = pk_cmul(QxZ, e8);
        const v2f QU0 = pk_cmul(Q, Ux0);
        const v2f QU1 = pk_cmul(Q, Ux1);
        v2f v9a; v9a.x = hv1.x; v9a.y = hv1.y;
        v2f v9b; v9b.x = hv1.z; v9b.y = hv1.w;
        const v2f v9s0 = t0 ? v9b : v9a, v9s1 = t0 ? v9a : v9b;
        v2f v10a; v10a.x = hv2.x; v10a.y = hv2.y;
        v2f v10b; v10b.x = hv2.z; v10b.y = hv2.w;
        v2f v11a; v11a.x = hv3.x; v11a.y = hv3.y;
        v2f v11b; v11b.x = hv3.z; v11b.y = hv3.w;
        const v2f P2_0 = pk_cmul(v10a, v11a), P2_1 = pk_cmul(v10a, v11b);
        const v2f P2_2 = pk_cmul(v10b, v11a), P2_3 = pk_cmul(v10b, v11b);
        #pragma unroll
        for (int k = 0; k < 8; ++k){
            const int g = k ^ (k >> 1);
            const v2f base = (k & 1) ? QU1 : QU0;
            const v2f w9   = (g & 4) ? v9s1 : v9s0;
            const v2f p2   = (g&3)==0 ? P2_0 : (g&3)==1 ? P2_1 : (g&3)==2 ? P2_2 : P2_3;
            amp[k] = pk_cmul(pk_cmul(base, w9), pk_cmul(p2, dd[k]));
        }

        // ---- 12 layer-1 RY gates in 4 rounds; T1/T2 wave-local (fence only) ----
        rot3ry<11>(amp, G);                      // wires 11,10,9 (j bits 0..2)
        #pragma unroll
        for (int k = 0; k < 8; ++k) S[bA ^ k] = amp[k];                 // T1 write (cfg A)
        asm volatile("" ::: "memory");
        #pragma unroll
        for (int k = 0; k < 8; ++k) amp[k] = S[bB ^ (9*k)];             // T1 read (cfg B)
        rot3ry<8>(amp, G);                       // wires 8,7,6 (j bits 3..5)
        #pragma unroll
        for (int k = 0; k < 8; ++k) S[bB ^ (9*k)] = amp[k];             // T2 write (in place)
        asm volatile("" ::: "memory");
        #pragma unroll
        for (int k = 0; k < 8; ++k) amp[k] = S[bC ^ ((k<<6) | ((k&3)<<3))]; // T2 read (cfg C)
        rot3ry<5>(amp, G);                       // wires 5,4,3 (j bits 6..8)
        #pragma unroll
        for (int k = 0; k < 8; ++k) S[bC ^ ((k<<6) | ((k&3)<<3))] = amp[k]; // T3 write (in place)
        __syncthreads();                         // barrier 1 (cross-wave transpose)
        #pragma unroll
        for (int k = 0; k < 8; ++k) amp[k] = S[bD + (k<<9)];            // T3 read (cfg D)
        rot3ry<2>(amp, G);                       // wires 2,1,0 (j bits 9..11)

        // ---- CNOT layer 1 folded into <Z_g>; j = (k<<9)|tid ----
        v2f a01; a01.x = 0.f; a01.y = 0.f;
        v2f a23; a23.x = 0.f; a23.y = 0.f;
        expk<0>(amp, a01, a23);
        float p0 = a01.x * sg0, p1 = a01.y * sg1;
        float p2s = a23.x * sg2, p3 = a23.y * sg3;
        p0 = wsum(p0); p1 = wsum(p1); p2s = wsum(p2s); p3 = wsum(p3);   // lane 63 has sums
        if (lane == 63) red4[wave] = make_float4(p0, p1, p2s, p3);
        // next step's x-wire vvx (consumed pre-T3-barrier; new values read post-barrier2)
        if (tid >= 128 && tid < 136){
            const int w  = tid - 128;
            const int tn = (t + 1 < TT) ? t + 1 : t;
            float sa, ca; __sincosf(0.5f*xs[tn*8 + w], &sa, &ca);
            const v2f M00=matp[w][0], M01=matp[w][1], M10=matp[w][2], M11=matp[w][3];
            v2f t0v; t0v.x = M00.x*ca + M01.y*sa; t0v.y = M00.y*ca - M01.x*sa;
            v2f t1v; t1v.x = M10.x*ca + M11.y*sa; t1v.y = M10.y*ca - M11.x*sa;
            vvx[w][0] = t0v; vvx[w][1] = t1v;
        }
        __syncthreads();                         // barrier 2 (red4 + vvx visibility)

        // ---- q-sum (LDS reads first so they overlap with the x-part below) ----
        float q0=0.f, q1=0.f, q2=0.f, q3=0.f;
        #pragma unroll
        for (int i = 0; i < 8; ++i){
            const float4 r = red4[i];
            q0 += r.x; q1 += r.y; q2 += r.z; q3 += r.w;
        }

        // ---- x-only product parts for t+1 (independent of q; fills exp-chain bubbles) ----
        {
            const v2f e2 = vf[ 4+s2], e3 = vf[ 6+s3], e4 = vf[ 8+s4];
            const v2f e5 = vf[10+s5], e6 = vf[12+s6], e7 = vf[14+s7];
            QxZ = pk_cmul(pk_cmul(pk_cmul(e2,e3), pk_cmul(e4,e5)),
                          pk_cmul(pk_cmul(e6,e7), Zphi));
            const v2f v0a = vf[0], v0b = vf[1], v1a = vf[2], v1b = vf[3];
            const v2f ua0 = t8 ? v0b : v0a,  ua1 = t8 ? v0a : v0b;
            const v2f ub0 = t78 ? v1b : v1a, ub1 = t78 ? v1a : v1b;
            Ux0 = pk_cmul(ua0, ub0); Ux1 = pk_cmul(ua1, ub1);
        }

        if (tid == 0) qh[t] = make_float4(q0, q1, q2, q3);   // history for epilogue

        // ---- tail: every lane computes its wire's chain; DPP quad-broadcast (no LDS) ----
        {
            const float fg = fsig (q0*WfC + bfC);
            const float ig = fsig (q1*WiC + biC);
            const float cg = ftanh(q2*WcC + bcC);
            const float og = fsig (q3*WoC + boC);
            c4 = fg*c4 + ig*cg;
            const float hj = og * ftanh(c4);
            float sa, ca; __sincosf(0.5f*hj, &sa, &ca);
            v4f hw;
            hw.x = M8w0.x*ca + M8w1.y*sa;  hw.y = M8w0.y*ca - M8w1.x*sa;
            hw.z = M8w2.x*ca + M8w3.y*sa;  hw.w = M8w2.y*ca - M8w3.x*sa;
            hv0 = qperm4<0x00>(hw); hv1 = qperm4<0x55>(hw);
            hv2 = qperm4<0xAA>(hw); hv3 = qperm4<0xFF>(hw);
        }
    }

    // ---- epilogue: per-channel LSTM scan over the q history (parallel over H) ----
    __syncthreads();
    if (tid < HH){
        const float wfE=Wf[tid], bfE=bfp[tid], wiE=Wi[tid], biE=bip[tid];
        const float wcE=Wc[tid], bcE=bcp[tid], woE=Wo[tid], boE=bop[tid];
        float cc = c0[b*HH + tid];
        float hh = 0.f;
        #pragma unroll 1
        for (int t = 0; t < TT; ++t){
            const float4 q = qh[t];
            const float fg = fsig (q.x*wfE + bfE);
            const float ig = fsig (q.y*wiE + biE);
            const float cg = ftanh(q.z*wcE + bcE);
            const float og = fsig (q.w*woE + boE);
            cc = fg*cc + ig*cg;
            hh = og * ftanh(cc);
        }
        out[b*HH + tid]         = hh;
        out[BB*HH + b*HH + tid] = cc;
    }
}

extern "C" void kernel_launch(void* const* d_in, const int* in_sizes, int n_in,
                              void* d_out, int out_size, void* d_ws, size_t ws_size,
                              hipStream_t stream)
{
    (void)in_sizes; (void)n_in; (void)d_ws; (void)ws_size; (void)out_size;
    const float* x  = (const float*)d_in[0];
    const float* h0 = (const float*)d_in[1];
    const float* c0 = (const float*)d_in[2];
    const float* qw = (const float*)d_in[3];
    const float* Wf = (const float*)d_in[4];
    const float* bf = (const float*)d_in[5];
    const float* Wi = (const float*)d_in[6];
    const float* bi = (const float*)d_in[7];
    const float* Wc = (const float*)d_in[8];
    const float* bc = (const float*)d_in[9];
    const float* Wo = (const float*)d_in[10];
    const float* bo = (const float*)d_in[11];
    qlstm_kernel<<<BB, NT, 0, stream>>>(x, h0, c0, qw, Wf, bf, Wi, bi,
                                        Wc, bc, Wo, bo, (float*)d_out);
}